// Round 6
// baseline (576.730 us; speedup 1.0000x reference)
//
#include <hip/hip_runtime.h>
#include <stdint.h>
#include <math.h>

// Match numpy's non-fused multiply-add rounding in distance/plane tests:
// a wrong argmin (or a boundary-mask flip) cascades into an O(1) output error.
// All d2 / plane expressions keep exactly these forms (contract off file-wide);
// p2 everywhere is x*x+y*y+z*z (left-assoc) — bit-identical to reference.
#pragma clang fp contract(off)

#define BLOCK 1024
#define NW (BLOCK / 64)
#define PT 8                    // points per thread per full-scan step
#define PB 4                    // entries per thread per list-scan step
#define MAX_ITERS 50
#define SOLO_CAP 2048           // below this, wave 0 finishes alone (no barriers)
#define NBINS 4096              // 16x16x16 Morton spatial bins
#define EPS_NORM 1e-8f
#define EPS_SEP (-1e-6f)

// R11 reframe: M=256 blocks on 256 CUs -> dur == MAX block time, not mean
// (occupancy 27% vs 50% inst. = mean lifetime 54% of max). The straggler does
// ~10-12 full-N passes before the LDS list engages; that IS the runtime.
// R5 lesson: ONE dwordx4/point is mandatory (3-dword loads re-serialized,
// VGPR 36, 548us); R3/R4 lesson: survivor state in LDS, ONE shared read-only
// array. R11 change: Morton-sort points into pk {x,y,z,orig_idx}; scanA uses
// wave-contiguous chunks (512 sorted pts/wave/step) with per-chunk live
// counts (sole-writer LDS) -> masked passes skip dead chunks' loads+mask IO.
// Survivors are spatially local, so straggler pass cost decays geometrically
// instead of staying at full N. Orig idx rides in .w: argmin stays exact
// (lexicographic (d2, orig_idx) == reference first-index argmin).
__device__ __forceinline__ int bin_of(float x, float y, float z) {
    int cx = (int)floorf((x + 3.5f) * (16.0f / 7.0f));
    int cy = (int)floorf((y + 3.5f) * (16.0f / 7.0f));
    int cz = (int)floorf((z + 3.5f) * (16.0f / 7.0f));
    cx = cx < 0 ? 0 : (cx > 15 ? 15 : cx);
    cy = cy < 0 ? 0 : (cy > 15 ? 15 : cy);
    cz = cz < 0 ? 0 : (cz > 15 ? 15 : cz);
    int code = 0;
    #pragma unroll
    for (int b = 0; b < 4; ++b) {
        code |= ((cx >> b) & 1) << (3 * b);
        code |= ((cy >> b) & 1) << (3 * b + 1);
        code |= ((cz >> b) & 1) << (3 * b + 2);
    }
    return code;
}

__global__ void zero_bins(int* __restrict__ binCnt) {
    const int i = blockIdx.x * blockDim.x + threadIdx.x;
    if (i < NBINS) binCnt[i] = 0;
}

__global__ void hist_bins(const float* __restrict__ pc, int* __restrict__ binCnt,
                          int N) {
    const int i = blockIdx.x * blockDim.x + threadIdx.x;
    if (i < N)
        atomicAdd(&binCnt[bin_of(pc[3*i+0], pc[3*i+1], pc[3*i+2])], 1);
}

// exclusive prefix over 4096 bins; 1024 threads x 4. Writes binCur (cursors).
__global__ void scan_bins(const int* __restrict__ binCnt,
                          int* __restrict__ binCur) {
    __shared__ int wsum[16];
    const int t = threadIdx.x, lane = t & 63, wv = t >> 6;
    const int v0 = binCnt[4*t+0], v1 = binCnt[4*t+1],
              v2 = binCnt[4*t+2], v3 = binCnt[4*t+3];
    const int s = v0 + v1 + v2 + v3;
    int incl = s;
    #pragma unroll
    for (int off = 1; off < 64; off <<= 1) {
        int o = __shfl_up(incl, off, 64);
        if (lane >= off) incl += o;
    }
    if (lane == 63) wsum[wv] = incl;
    __syncthreads();
    if (t == 0) {
        int acc = 0;
        for (int w = 0; w < 16; ++w) { int x = wsum[w]; wsum[w] = acc; acc += x; }
    }
    __syncthreads();
    const int excl = incl - s + wsum[wv];
    binCur[4*t+0] = excl;
    binCur[4*t+1] = excl + v0;
    binCur[4*t+2] = excl + v0 + v1;
    binCur[4*t+3] = excl + v0 + v1 + v2;
}

__global__ void scatter_bins(const float* __restrict__ pc,
                             float4* __restrict__ pk,
                             int* __restrict__ binCur, int N) {
    const int i = blockIdx.x * blockDim.x + threadIdx.x;
    if (i < N) {
        const float x = pc[3*i+0], y = pc[3*i+1], z = pc[3*i+2];
        const int pos = atomicAdd(&binCur[bin_of(x, y, z)], 1);
        float4 v; v.x = x; v.y = y; v.z = z; v.w = __int_as_float(i);
        pk[pos] = v;
    }
}

__global__ void pack_identity(const float* __restrict__ pc,
                              float4* __restrict__ pk, int N) {
    const int i = blockIdx.x * blockDim.x + threadIdx.x;
    if (i < N) {
        float4 v; v.x = pc[3*i+0]; v.y = pc[3*i+1]; v.z = pc[3*i+2];
        v.w = __int_as_float(i);
        pk[i] = v;
    }
}

// One block per target. Tiers: full-N bitmask scans (chunk-skipped) ->
// LDS index list -> LDS coord solo tail (wave 0).
// PK=true: pk float4 {x,y,z,orig}; PK=false: raw pc fallback (no ws).
template <bool PK>
__global__ __launch_bounds__(BLOCK) void convex_plane_kernel(
    const float* __restrict__ pc, const float4* __restrict__ pk,
    const float* __restrict__ tg,
    float* __restrict__ out, int N, int M, int CAP, int stepsA)
{
    extern __shared__ uint32_t smem[];
    const int tid  = threadIdx.x;
    const int lane = tid & 63;
    const int wv   = tid >> 6;
    const int m    = blockIdx.x;

    const int maskW = stepsA * (PT * BLOCK / 32);  // mask words (256/step)
    uint32_t* mask  = smem;                        // [maskW]
    int*      list  = (int*)(smem + maskW);        // [CAP]
    float*    red_d = (float*)(list + CAP);        // [NW]
    int*      red_i = (int*)(red_d + NW);          // [NW]
    int*      cw    = red_i + NW;                  // [NW]
    int*      bcast = cw + NW;                     // [2] {argmin idx, count}
    int*      cnt   = bcast + 2;                   // [1] list-append cursor
    int*      chk   = cnt + 1;                     // [stepsA*NW] chunk live cnt

    const float tx = tg[3*m+0], ty = tg[3*m+1], tz = tg[3*m+2];
    const float t2 = tx*tx + ty*ty + tz*tz;

    float* out_a = out;
    float* out_b = out + (size_t)MAX_ITERS * (size_t)M * 3;

    // cross-wave finish: lexicographic (d2,orig) argmin + count sum.
    auto finish = [&](float dmin, int imin, int mycnt, bool cntFromCursor) -> int2 {
        #pragma unroll
        for (int off = 32; off > 0; off >>= 1) {
            float od = __shfl_down(dmin, off, 64);
            int   oi = __shfl_down(imin, off, 64);
            int   oc = __shfl_down(mycnt, off, 64);
            if (od < dmin || (od == dmin && oi < imin)) { dmin = od; imin = oi; }
            mycnt += oc;
        }
        if (lane == 0) { red_d[wv] = dmin; red_i[wv] = imin; cw[wv] = mycnt; }
        __syncthreads();
        if (wv == 0) {
            float bd = (lane < NW) ? red_d[lane] : INFINITY;
            int   bi = (lane < NW) ? red_i[lane] : 0;
            int   c  = (lane < NW) ? cw[lane]    : 0;
            #pragma unroll
            for (int off = 8; off > 0; off >>= 1) {
                float od = __shfl_down(bd, off, 64);
                int   oi = __shfl_down(bi, off, 64);
                int   oc = __shfl_down(c,  off, 64);
                if (od < bd || (od == bd && oi < bi)) { bd = od; bi = oi; }
                c += oc;
            }
            if (lane == 0) { bcast[0] = bi; bcast[1] = cntFromCursor ? cnt[0] : c; }
        }
        __syncthreads();
        int2 r; r.x = bcast[0]; r.y = bcast[1];
        return r;
    };

    // Phase A: full-N scan; wave wv owns chunk [s*8192 + wv*512, +512).
    // mode 0: all live, no plane test, no mask write (initial argmin)
    // mode 1: all live, test plane, write mask + chunk counts
    // mode 2: read mask (skip dead chunks), test, write mask + chunk counts
    auto scanA = [&](int mode, bool build,
                     float ax, float ay, float az, float b) -> int2 {
        if (tid == 0) cnt[0] = 0;
        __syncthreads();
        float dmin = INFINITY;
        int   imin = 0;
        int   mycnt = 0;
        for (int s = 0; s < stepsA; ++s) {
            const int cid = s * NW + wv;
            if (mode == 2 && chk[cid] == 0) continue;   // dead chunk: skip all
            const int pbase = s * (PT * BLOCK) + wv * (PT * 64) + lane;
            const int wwb   = s * (PT * BLOCK / 32) + wv * (PT * 2);
            uint32_t livem = 0;
            if (mode == 2) {
                #pragma unroll
                for (int j = 0; j < PT; ++j) {          // broadcast reads
                    uint32_t w = mask[wwb + j * 2 + (lane >> 5)];
                    livem |= ((w >> (lane & 31)) & 1u) << j;
                }
            } else {
                #pragma unroll
                for (int j = 0; j < PT; ++j)
                    if (pbase + j * 64 < N) livem |= (1u << j);
            }
            // UNCONDITIONAL clamped dwordx4 loads (R5: never split these).
            float px[PT], py[PT], pz[PT]; int ov[PT];
            if constexpr (PK) {
                #pragma unroll
                for (int j = 0; j < PT; ++j) {
                    int ip = pbase + j * 64;
                    ip = ip < N ? ip : N - 1;
                    const float4 v = pk[ip];
                    px[j] = v.x; py[j] = v.y; pz[j] = v.z;
                    ov[j] = __float_as_int(v.w);
                }
            } else {
                #pragma unroll
                for (int j = 0; j < PT; ++j) {
                    int ip = pbase + j * 64;
                    ip = ip < N ? ip : N - 1;
                    const float* p = pc + 3 * (size_t)ip;
                    px[j] = p[0]; py[j] = p[1]; pz[j] = p[2];
                    ov[j] = ip;
                }
            }
            uint32_t keepm = 0;
            #pragma unroll
            for (int j = 0; j < PT; ++j) {
                if ((livem >> j) & 1u) {
                    bool keep;
                    if (mode == 0) keep = true;
                    else {
                        float dt = ax*px[j] + ay*py[j] + az*pz[j] - b;
                        keep = (dt < EPS_SEP);          // !(dt >= EPS_SEP)
                    }
                    if (keep) {
                        keepm |= (1u << j);
                        float p2 = px[j]*px[j] + py[j]*py[j] + pz[j]*pz[j];
                        float tp = tx*px[j] + ty*py[j] + tz*pz[j];
                        float d2 = t2 + p2 - 2.0f*tp;   // reference's exact form
                        if (d2 < dmin || (d2 == dmin && ov[j] < imin)) {
                            dmin = d2; imin = ov[j];
                        }
                    }
                }
            }
            mycnt += (int)__popc(keepm);
            if (mode != 0) {
                #pragma unroll
                for (int j = 0; j < PT; ++j) {          // 2 writer lanes/wave/j
                    unsigned long long bal = __ballot(((keepm >> j) & 1u) != 0u);
                    if (lane == 0)       mask[wwb + j*2]     = (uint32_t)bal;
                    else if (lane == 32) mask[wwb + j*2 + 1] = (uint32_t)(bal >> 32);
                }
                int wsumc = (int)__popc(keepm);         // chunk live count
                #pragma unroll
                for (int off = 32; off > 0; off >>= 1)
                    wsumc += __shfl_down(wsumc, off, 64);
                if (lane == 0) chk[cid] = wsumc;        // sole writer: wave wv
            }
            if (build) {                                // compact survivors
                int c = (int)__popc(keepm);
                int incl = c;
                #pragma unroll
                for (int off = 1; off < 64; off <<= 1) {
                    int o = __shfl_up(incl, off, 64);
                    if (lane >= off) incl += o;
                }
                const int excl = incl - c;
                const int tot  = __shfl(incl, 63, 64);
                int wb = 0;
                if (lane == 0) wb = atomicAdd(cnt, tot);
                wb = __shfl(wb, 0, 64);
                int pos = wb + excl;
                #pragma unroll
                for (int j = 0; j < PT; ++j) {
                    if ((keepm >> j) & 1u) {
                        if (pos < CAP) list[pos] = pbase + j * 64;  // sorted pos
                        ++pos;
                    }
                }
            }
        }
        return finish(dmin, imin, mycnt, false);
    };

    // Phase B: list scan (list holds SORTED positions; orig idx from pk.w),
    // in-place re-compaction (reads barrier-complete before appends; cursor
    // stays below any unread segment).
    auto scanB = [&](int count, float ax, float ay, float az, float b) -> int2 {
        if (tid == 0) cnt[0] = 0;
        __syncthreads();
        float dmin = INFINITY;
        int   imin = 0;
        const int per = BLOCK * PB;
        const int bsteps = (count + per - 1) / per;
        for (int s = 0; s < bsteps; ++s) {
            int jv[PB]; float xv[PB], yv[PB], zv[PB]; int ov[PB]; float d2v[PB];
            #pragma unroll
            for (int q = 0; q < PB; ++q) {              // unconditional clamped
                int e = s * per + q * BLOCK + tid;
                e = e < count ? e : count - 1;
                jv[q] = list[e];
            }
            #pragma unroll
            for (int q = 0; q < PB; ++q) {              // dwordx4 up front
                if constexpr (PK) {
                    const float4 v = pk[jv[q]];
                    xv[q] = v.x; yv[q] = v.y; zv[q] = v.z;
                    ov[q] = __float_as_int(v.w);
                } else {
                    const float* p = pc + 3 * (size_t)jv[q];
                    xv[q] = p[0]; yv[q] = p[1]; zv[q] = p[2];
                    ov[q] = jv[q];
                }
            }
            uint32_t keepm = 0;
            #pragma unroll
            for (int q = 0; q < PB; ++q) {
                const int e = s * per + q * BLOCK + tid;
                if (e < count) {
                    float dt = ax*xv[q] + ay*yv[q] + az*zv[q] - b;
                    if (dt < EPS_SEP) {
                        keepm |= (1u << q);
                        float p2 = xv[q]*xv[q] + yv[q]*yv[q] + zv[q]*zv[q];
                        float tp = tx*xv[q] + ty*yv[q] + tz*zv[q];
                        d2v[q] = t2 + p2 - 2.0f*tp;
                    }
                }
            }
            __syncthreads();                            // reads before appends
            int c = (int)__popc(keepm);
            int incl = c;
            #pragma unroll
            for (int off = 1; off < 64; off <<= 1) {
                int o = __shfl_up(incl, off, 64);
                if (lane >= off) incl += o;
            }
            const int excl = incl - c;
            const int tot  = __shfl(incl, 63, 64);
            int wb = 0;
            if (lane == 0) wb = atomicAdd(cnt, tot);
            wb = __shfl(wb, 0, 64);
            int pos = wb + excl;
            #pragma unroll
            for (int q = 0; q < PB; ++q) {
                if ((keepm >> q) & 1u) {
                    list[pos] = jv[q];
                    if (d2v[q] < dmin || (d2v[q] == dmin && ov[q] < imin)) {
                        dmin = d2v[q]; imin = ov[q];
                    }
                    ++pos;
                }
            }
        }
        __syncthreads();                                // appends/atomics done
        return finish(dmin, imin, 0, true);             // count from cursor
    };

    bool comp = false;
    int2 rc = scanA(0, false, 0.f, 0.f, 0.f, 0.f);
    int idx = rc.x, count = rc.y;                       // count = N here

    for (int k = 0; k < MAX_ITERS; ++k) {
        // Solo tail: wave 0 finishes barrier-free on LDS-resident coords.
        if (comp && count <= SOLO_CAP) {
            // Coord arrays in the dead upper list region:
            // SOLO_CAP + 3*SOLO_CAP <= CAP for CAP=32768 and CAP=8192.
            float* lx = (float*)(list + SOLO_CAP);
            float* ly = lx + SOLO_CAP;
            float* lz = ly + SOLO_CAP;
            for (int e = tid; e < count; e += BLOCK) {  // one gather; convert
                if constexpr (PK) {                     // list -> orig idx
                    const float4 v = pk[list[e]];
                    lx[e] = v.x; ly[e] = v.y; lz[e] = v.z;
                    list[e] = __float_as_int(v.w);
                } else {
                    const float* p = pc + 3 * (size_t)list[e];
                    lx[e] = p[0]; ly[e] = p[1]; lz[e] = p[2];
                }
            }
            __syncthreads();                            // fill done
            if (wv != 0) return;                        // LDS persists
            for (; k < MAX_ITERS; ++k) {
                const float* cp = pc + 3 * (size_t)idx;
                const float cx = cp[0], cy = cp[1], cz = cp[2];
                const float vx = cx - tx, vy = cy - ty, vz = cz - tz;
                const float nrm = sqrtf(vx*vx + vy*vy + vz*vz);
                const float den = nrm + EPS_NORM;
                const float ax = vx / den, ay = vy / den, az = vz / den;
                const float b  = ax*cx + ay*cy + az*cz;
                if (count == 0) {                       // constant tail
                    for (int q = lane; q < MAX_ITERS - k; q += 64) {
                        const int kk = k + q;
                        const size_t oa = ((size_t)kk * M + m) * 3;
                        out_a[oa+0] = ax; out_a[oa+1] = ay; out_a[oa+2] = az;
                        out_b[(size_t)kk * M + m] = b;
                    }
                    return;
                }
                if (lane == 0) {
                    const size_t oa = ((size_t)k * M + m) * 3;
                    out_a[oa+0] = ax; out_a[oa+1] = ay; out_a[oa+2] = az;
                    out_b[(size_t)k * M + m] = b;
                }
                if (k + 1 < MAX_ITERS) {
                    float dmin = INFINITY; int imin = 0; int wcur = 0;
                    for (int e0 = 0; e0 < count; e0 += 64) {
                        const int e = e0 + lane;
                        bool keep = false; int j = 0;
                        float d2v = 0.f, px = 0.f, py = 0.f, pz = 0.f;
                        if (e < count) {
                            j = list[e];
                            px = lx[e]; py = ly[e]; pz = lz[e];
                            float dt = ax*px + ay*py + az*pz - b;
                            if (dt < EPS_SEP) {
                                keep = true;
                                float p2 = px*px + py*py + pz*pz;
                                float tp = tx*px + ty*py + tz*pz;
                                d2v = t2 + p2 - 2.0f*tp;
                            }
                        }
                        // in-place compact: pos < wcur+64 <= e0+64; chunk
                        // [e0,e0+64) already in registers.
                        unsigned long long bal = __ballot(keep);
                        int pos = wcur + (int)__popcll(bal & ((1ull << lane) - 1ull));
                        if (keep) {
                            list[pos] = j;
                            lx[pos] = px; ly[pos] = py; lz[pos] = pz;
                            if (d2v < dmin || (d2v == dmin && j < imin)) {
                                dmin = d2v; imin = j;
                            }
                        }
                        wcur += (int)__popcll(bal);
                    }
                    #pragma unroll
                    for (int off = 32; off > 0; off >>= 1) {
                        float od = __shfl_down(dmin, off, 64);
                        int   oi = __shfl_down(imin, off, 64);
                        if (od < dmin || (od == dmin && oi < imin)) { dmin = od; imin = oi; }
                    }
                    idx = __shfl(imin, 0, 64);
                    count = wcur;
                }
            }
            return;
        }

        const float* cp = pc + 3 * (size_t)idx;         // idx = ORIGINAL index
        const float cx = cp[0], cy = cp[1], cz = cp[2];
        const float vx = cx - tx, vy = cy - ty, vz = cz - tz;
        const float nrm = sqrtf(vx*vx + vy*vy + vz*vz);
        const float den = nrm + EPS_NORM;
        const float ax = vx / den, ay = vy / den, az = vz / den;
        const float b  = ax*cx + ay*cy + az*cz;         // b = sum(a * closest)

        if (count == 0) {                               // constant tail
            for (int q = tid; q < MAX_ITERS - k; q += BLOCK) {
                const int kk = k + q;
                const size_t oa = ((size_t)kk * M + m) * 3;
                out_a[oa+0] = ax; out_a[oa+1] = ay; out_a[oa+2] = az;
                out_b[(size_t)kk * M + m] = b;
            }
            return;
        }
        if (tid == 0) {
            const size_t oa = ((size_t)k * M + m) * 3;
            out_a[oa+0] = ax; out_a[oa+1] = ay; out_a[oa+2] = az;
            out_b[(size_t)k * M + m] = b;
        }
        if (k + 1 < MAX_ITERS) {                        // last update unobservable
            if (comp) {
                rc = scanB(count, ax, ay, az, b);
            } else {
                // early attempts: a failed build costs only a prefix scan
                const bool build = (count <= (5 * CAP) / 2);
                rc = scanA(k == 0 ? 1 : 2, build, ax, ay, az, b);
                if (build && rc.y <= CAP) comp = true;
            }
            idx = rc.x; count = rc.y;
        }
    }
}

extern "C" void kernel_launch(void* const* d_in, const int* in_sizes, int n_in,
                              void* d_out, int out_size, void* d_ws, size_t ws_size,
                              hipStream_t stream) {
    const float* pc = (const float*)d_in[0];
    const float* tg = (const float*)d_in[1];
    float* out = (float*)d_out;
    const int N = in_sizes[0] / 3;
    const int M = in_sizes[1] / 3;
    const int stepsA = (N + BLOCK * PT - 1) / (BLOCK * PT);
    const size_t maskB  = (size_t)stepsA * (PT * BLOCK / 32) * sizeof(uint32_t);
    const size_t fixedB = NW * (2 * sizeof(int) + sizeof(float)) + 3 * sizeof(int)
                        + (size_t)stepsA * NW * sizeof(int);   // + chunk counts
    const size_t pkB    = (size_t)N * sizeof(float4);
    const size_t binB   = 2 * (size_t)NBINS * sizeof(int);

    int wsmode = 0;                                     // 0 raw, 1 identity, 2 sorted
    if (d_ws && ws_size >= pkB + binB) wsmode = 2;
    else if (d_ws && ws_size >= pkB)   wsmode = 1;
    float4* pk     = (float4*)d_ws;
    int*    binCnt = (int*)((char*)d_ws + pkB);
    int*    binCur = binCnt + NBINS;

    int CAP = 32768;                                    // 128 KB list
    size_t smem = maskB + (size_t)CAP * sizeof(int) + fixedB;
    const void* fn = (wsmode >= 1) ? (const void*)convex_plane_kernel<true>
                                   : (const void*)convex_plane_kernel<false>;
    if (hipFuncSetAttribute(fn, hipFuncAttributeMaxDynamicSharedMemorySize,
                            (int)smem) != hipSuccess) {
        CAP = 8192;                                     // default 64 KB budget
        smem = maskB + (size_t)CAP * sizeof(int) + fixedB;
    }
    if (wsmode == 2) {
        const int tpb = 256;
        zero_bins<<<(NBINS + tpb - 1) / tpb, tpb, 0, stream>>>(binCnt);
        hist_bins<<<(N + tpb - 1) / tpb, tpb, 0, stream>>>(pc, binCnt, N);
        scan_bins<<<1, 1024, 0, stream>>>(binCnt, binCur);
        scatter_bins<<<(N + tpb - 1) / tpb, tpb, 0, stream>>>(pc, pk, binCur, N);
        convex_plane_kernel<true><<<M, BLOCK, smem, stream>>>(
            pc, pk, tg, out, N, M, CAP, stepsA);
    } else if (wsmode == 1) {
        pack_identity<<<(N + 255) / 256, 256, 0, stream>>>(pc, pk, N);
        convex_plane_kernel<true><<<M, BLOCK, smem, stream>>>(
            pc, pk, tg, out, N, M, CAP, stepsA);
    } else {
        convex_plane_kernel<false><<<M, BLOCK, smem, stream>>>(
            pc, nullptr, tg, out, N, M, CAP, stepsA);
    }
}

// Round 7
// 572.563 us; speedup vs baseline: 1.0073x; 1.0073x over previous
//
#include <hip/hip_runtime.h>
#include <stdint.h>
#include <math.h>

// Match numpy's non-fused multiply-add rounding in distance/plane tests.
// All d2 / plane expressions keep exactly these forms (contract off file-wide);
// p2 everywhere is x*x+y*y+z*z — bit-identical to reference.
#pragma clang fp contract(off)

#define BLOCK 1024
#define NW 16                   // waves per block
#define PT 8                    // points per lane per chunk (8*64 = 512/chunk)
#define MAX_ITERS 50
#define SOLO_CAP 2048
#define NBINS 4096              // 16^3 Morton bins for the spatial sort
#define EPS_NORM 1e-8f
#define EPS_SEP (-1e-6f)
#define SLACK_ABS 1e-3f         // conservative classify margin >> fp error
#define SLACK_REL 1e-5f         // scale-relative term (re-poison safety)

// R12: per-point d2 is iteration-invariant and the survivor set only shrinks,
// so cache per-chunk (dmin, imin, count, AABB). Each cut plane classifies a
// chunk by its AABB: strictly keep-side -> reuse cached state (NO scan);
// strictly die-side -> count=0 wholesale; only straddling chunks rescan.
// Cut planes are tangent caps -> straddle set is a surface, killing the
// Sum(live)x16B/iter floor that bounded R6 (431us main). Classification is a
// conservative ROUTER only: every value consumed comes from the exact
// per-point expression forms, so results stay bit-identical. AABBs tighten on
// every rescan. Sort prep: memsetAsync + vectorized hist/scatter (R6 prep
// chain cost ~115us on 4 scalar kernels).
__device__ __forceinline__ int bin_of(float x, float y, float z) {
    int cx = (int)floorf((x + 3.5f) * (16.0f / 7.0f));
    int cy = (int)floorf((y + 3.5f) * (16.0f / 7.0f));
    int cz = (int)floorf((z + 3.5f) * (16.0f / 7.0f));
    cx = cx < 0 ? 0 : (cx > 15 ? 15 : cx);
    cy = cy < 0 ? 0 : (cy > 15 ? 15 : cy);
    cz = cz < 0 ? 0 : (cz > 15 ? 15 : cz);
    int code = 0;
    #pragma unroll
    for (int b = 0; b < 4; ++b) {
        code |= ((cx >> b) & 1) << (3 * b);
        code |= ((cy >> b) & 1) << (3 * b + 1);
        code |= ((cz >> b) & 1) << (3 * b + 2);
    }
    return code;
}

__global__ void hist_bins(const float* __restrict__ pc, int* __restrict__ binCnt,
                          int N) {
    const int t = blockIdx.x * blockDim.x + threadIdx.x;
    const int base = t * 4;
    if (base + 3 < N) {
        const float4* p4 = (const float4*)pc;       // 3 dwordx4 = 4 points
        const float4 a = p4[3*t+0], b = p4[3*t+1], c = p4[3*t+2];
        atomicAdd(&binCnt[bin_of(a.x, a.y, a.z)], 1);
        atomicAdd(&binCnt[bin_of(a.w, b.x, b.y)], 1);
        atomicAdd(&binCnt[bin_of(b.z, b.w, c.x)], 1);
        atomicAdd(&binCnt[bin_of(c.y, c.z, c.w)], 1);
    } else {
        for (int i = base; i < N; ++i)
            atomicAdd(&binCnt[bin_of(pc[3*i], pc[3*i+1], pc[3*i+2])], 1);
    }
}

// exclusive prefix over 4096 bins; 1024 threads x 4. Writes binCur (cursors).
__global__ void scan_bins(const int* __restrict__ binCnt,
                          int* __restrict__ binCur) {
    __shared__ int wsum[16];
    const int t = threadIdx.x, lane = t & 63, wv = t >> 6;
    const int v0 = binCnt[4*t+0], v1 = binCnt[4*t+1],
              v2 = binCnt[4*t+2], v3 = binCnt[4*t+3];
    const int s = v0 + v1 + v2 + v3;
    int incl = s;
    #pragma unroll
    for (int off = 1; off < 64; off <<= 1) {
        int o = __shfl_up(incl, off, 64);
        if (lane >= off) incl += o;
    }
    if (lane == 63) wsum[wv] = incl;
    __syncthreads();
    if (t == 0) {
        int acc = 0;
        for (int w = 0; w < 16; ++w) { int x = wsum[w]; wsum[w] = acc; acc += x; }
    }
    __syncthreads();
    const int excl = incl - s + wsum[wv];
    binCur[4*t+0] = excl;
    binCur[4*t+1] = excl + v0;
    binCur[4*t+2] = excl + v0 + v1;
    binCur[4*t+3] = excl + v0 + v1 + v2;
}

__global__ void scatter_bins(const float* __restrict__ pc,
                             float4* __restrict__ pk,
                             int* __restrict__ binCur, int N) {
    const int t = blockIdx.x * blockDim.x + threadIdx.x;
    const int base = t * 4;
    if (base + 3 < N) {
        const float4* p4 = (const float4*)pc;
        const float4 a = p4[3*t+0], b = p4[3*t+1], c = p4[3*t+2];
        float x[4] = {a.x, a.w, b.z, c.y};
        float y[4] = {a.y, b.x, b.w, c.z};
        float z[4] = {a.z, b.y, c.x, c.w};
        #pragma unroll
        for (int q = 0; q < 4; ++q) {
            const int pos = atomicAdd(&binCur[bin_of(x[q], y[q], z[q])], 1);
            float4 v; v.x = x[q]; v.y = y[q]; v.z = z[q];
            v.w = __int_as_float(base + q);
            pk[pos] = v;
        }
    } else {
        for (int i = base; i < N; ++i) {
            const float xx = pc[3*i], yy = pc[3*i+1], zz = pc[3*i+2];
            const int pos = atomicAdd(&binCur[bin_of(xx, yy, zz)], 1);
            float4 v; v.x = xx; v.y = yy; v.z = zz; v.w = __int_as_float(i);
            pk[pos] = v;
        }
    }
}

__global__ void pack_identity(const float* __restrict__ pc,
                              float4* __restrict__ pk, int N) {
    const int i = blockIdx.x * blockDim.x + threadIdx.x;
    if (i < N) {
        float4 v; v.x = pc[3*i+0]; v.y = pc[3*i+1]; v.z = pc[3*i+2];
        v.w = __int_as_float(i);
        pk[i] = v;
    }
}

// One block per target. Per-chunk cached state + AABB classify; mask holds
// per-point live bits for boundary rescans; solo tail for the endgame.
template <bool PK>
__global__ __launch_bounds__(BLOCK) void convex_plane_kernel(
    const float* __restrict__ pc, const float4* __restrict__ pk,
    const float* __restrict__ tg,
    float* __restrict__ out, int N, int M, int stepsA)
{
    extern __shared__ uint32_t smem[];
    const int tid  = threadIdx.x;
    const int lane = tid & 63;
    const int wv   = tid >> 6;
    const int m    = blockIdx.x;

    const int NC    = stepsA * NW;                  // chunks (512 pts each)
    const int maskW = stepsA * (PT * BLOCK / 32);   // live-bit words
    uint32_t* mask = smem;                          // [maskW]
    float* mnx = (float*)(mask + maskW);            // [NC] AABB mins
    float* mny = mnx + NC;
    float* mnz = mny + NC;
    float* mxx = mnz + NC;                          // [NC] AABB maxs
    float* mxy = mxx + NC;
    float* mxz = mxy + NC;
    float* cdm = mxz + NC;                          // [NC] cached min d2
    int*   cim = (int*)(cdm + NC);                  // [NC] cached argmin (orig)
    int*   ccn = cim + NC;                          // [NC] cached live count
    float* red_d = (float*)(ccn + NC);              // [NW]
    int*   red_i = (int*)(red_d + NW);              // [NW]
    int*   cw    = red_i + NW;                      // [NW]
    int*   bcast = cw + NW;                         // [2]
    int*   cnt   = bcast + 2;                       // [1]
    int*   slist = cnt + 1;                         // [SOLO_CAP] orig idx
    float* lx = (float*)(slist + SOLO_CAP);         // [SOLO_CAP] coords
    float* ly = lx + SOLO_CAP;
    float* lz = ly + SOLO_CAP;

    const float tx = tg[3*m+0], ty = tg[3*m+1], tz = tg[3*m+2];
    const float t2 = tx*tx + ty*ty + tz*tz;

    float* out_a = out;
    float* out_b = out + (size_t)MAX_ITERS * (size_t)M * 3;

    // 8 points of own chunk: UNCONDITIONAL clamped dwordx4 (R5/R6 law).
    auto ld8 = [&](int pbase, float px[PT], float py[PT], float pz[PT],
                   int ov[PT]) {
        #pragma unroll
        for (int j = 0; j < PT; ++j) {
            int ip = pbase + j * 64;
            ip = ip < N ? ip : N - 1;
            if constexpr (PK) {
                const float4 v = pk[ip];
                px[j] = v.x; py[j] = v.y; pz[j] = v.z;
                ov[j] = __float_as_int(v.w);
            } else {
                const float* p = pc + 3 * (size_t)ip;
                px[j] = p[0]; py[j] = p[1]; pz[j] = p[2];
                ov[j] = ip;
            }
        }
    };

    // block argmin+count from per-chunk cached state (barrier-protected).
    auto finish = [&]() -> int2 {
        __syncthreads();                            // all chunk writes visible
        float bd = INFINITY; int bi = 0; int cs = 0;
        for (int l = lane; l < stepsA; l += 64) {
            const int c = wv + NW * l;              // own chunks
            const float d = cdm[c]; const int i = cim[c];
            if (d < bd || (d == bd && i < bi)) { bd = d; bi = i; }
            cs += ccn[c];
        }
        #pragma unroll
        for (int off = 32; off > 0; off >>= 1) {
            float od = __shfl_down(bd, off, 64);
            int   oi = __shfl_down(bi, off, 64);
            int   oc = __shfl_down(cs, off, 64);
            if (od < bd || (od == bd && oi < bi)) { bd = od; bi = oi; }
            cs += oc;
        }
        if (lane == 0) { red_d[wv] = bd; red_i[wv] = bi; cw[wv] = cs; }
        __syncthreads();
        if (wv == 0) {
            float d = (lane < NW) ? red_d[lane] : INFINITY;
            int   i = (lane < NW) ? red_i[lane] : 0;
            int   c = (lane < NW) ? cw[lane]    : 0;
            #pragma unroll
            for (int off = 8; off > 0; off >>= 1) {
                float od = __shfl_down(d, off, 64);
                int   oi = __shfl_down(i, off, 64);
                int   oc = __shfl_down(c, off, 64);
                if (od < d || (od == d && oi < i)) { d = od; i = oi; }
                c += oc;
            }
            if (lane == 0) { bcast[0] = i; bcast[1] = c; }
        }
        __syncthreads();
        int2 r; r.x = bcast[0]; r.y = bcast[1];
        return r;
    };

    // chunk scan epilogue: reduce partials, write chunk state + tightened AABB.
    auto writeChunk = [&](int c, uint32_t keepm,
                          float dmin, int imin,
                          float px[PT], float py[PT], float pz[PT]) {
        float nx = INFINITY, ny = INFINITY, nz = INFINITY;
        float Xx = -INFINITY, Xy = -INFINITY, Xz = -INFINITY;
        #pragma unroll
        for (int j = 0; j < PT; ++j) {
            if ((keepm >> j) & 1u) {
                nx = fminf(nx, px[j]); ny = fminf(ny, py[j]); nz = fminf(nz, pz[j]);
                Xx = fmaxf(Xx, px[j]); Xy = fmaxf(Xy, py[j]); Xz = fmaxf(Xz, pz[j]);
            }
        }
        int cntl = (int)__popc(keepm);
        #pragma unroll
        for (int off = 32; off > 0; off >>= 1) {
            float od = __shfl_down(dmin, off, 64);
            int   oi = __shfl_down(imin, off, 64);
            if (od < dmin || (od == dmin && oi < imin)) { dmin = od; imin = oi; }
            cntl += __shfl_down(cntl, off, 64);
            nx = fminf(nx, __shfl_down(nx, off, 64));
            ny = fminf(ny, __shfl_down(ny, off, 64));
            nz = fminf(nz, __shfl_down(nz, off, 64));
            Xx = fmaxf(Xx, __shfl_down(Xx, off, 64));
            Xy = fmaxf(Xy, __shfl_down(Xy, off, 64));
            Xz = fmaxf(Xz, __shfl_down(Xz, off, 64));
        }
        if (lane == 0) {
            cdm[c] = dmin; cim[c] = imin; ccn[c] = cntl;
            mnx[c] = nx; mny[c] = ny; mnz[c] = nz;
            mxx[c] = Xx; mxy[c] = Xy; mxz[c] = Xz;
        }
    };

    // initial pass: mask=in-range, AABB + per-chunk argmin/count.
    auto initScan = [&]() {
        for (int s = 0; s < stepsA; ++s) {
            const int c = s * NW + wv;
            const int pbase = s * (PT * BLOCK) + wv * (PT * 64) + lane;
            const int wwb   = s * (PT * BLOCK / 32) + wv * (PT * 2);
            uint32_t livem = 0;
            #pragma unroll
            for (int j = 0; j < PT; ++j)
                if (pbase + j * 64 < N) livem |= (1u << j);
            float px[PT], py[PT], pz[PT]; int ov[PT];
            ld8(pbase, px, py, pz, ov);
            float dmin = INFINITY; int imin = 0;
            #pragma unroll
            for (int j = 0; j < PT; ++j) {
                if ((livem >> j) & 1u) {
                    float p2 = px[j]*px[j] + py[j]*py[j] + pz[j]*pz[j];
                    float tp = tx*px[j] + ty*py[j] + tz*pz[j];
                    float d2 = t2 + p2 - 2.0f*tp;       // exact reference form
                    if (d2 < dmin || (d2 == dmin && ov[j] < imin)) {
                        dmin = d2; imin = ov[j];
                    }
                }
            }
            #pragma unroll
            for (int j = 0; j < PT; ++j) {              // mask init
                unsigned long long bal = __ballot(((livem >> j) & 1u) != 0u);
                if (lane == 0)       mask[wwb + j*2]     = (uint32_t)bal;
                else if (lane == 32) mask[wwb + j*2 + 1] = (uint32_t)(bal >> 32);
            }
            writeChunk(c, livem, dmin, imin, px, py, pz);
        }
    };

    // masked step: AABB-classify; rescan straddling chunks only.
    auto stepScan = [&](float ax, float ay, float az, float b) {
        for (int s = 0; s < stepsA; ++s) {
            const int c = s * NW + wv;
            if (ccn[c] == 0) continue;                  // dead chunk
            const float ubx = fmaxf(ax*mnx[c], ax*mxx[c]);
            const float uby = fmaxf(ay*mny[c], ay*mxy[c]);
            const float ubz = fmaxf(az*mnz[c], az*mxz[c]);
            const float ub  = (ubx + uby + ubz) - b;
            const float sl  = SLACK_ABS + SLACK_REL * (fabsf(ub) + fabsf(b));
            if (ub < EPS_SEP - sl) continue;            // certainly all keep
            const float lbx = fminf(ax*mnx[c], ax*mxx[c]);
            const float lby = fminf(ay*mny[c], ay*mxy[c]);
            const float lbz = fminf(az*mnz[c], az*mxz[c]);
            const float lb  = (lbx + lby + lbz) - b;
            const float sl2 = SLACK_ABS + SLACK_REL * (fabsf(lb) + fabsf(b));
            if (lb >= EPS_SEP + sl2) {                  // certainly all die
                if (lane == 0) { ccn[c] = 0; cdm[c] = INFINITY; }
                continue;
            }
            // boundary: exact per-point rescan
            const int pbase = s * (PT * BLOCK) + wv * (PT * 64) + lane;
            const int wwb   = s * (PT * BLOCK / 32) + wv * (PT * 2);
            uint32_t livem = 0;
            #pragma unroll
            for (int j = 0; j < PT; ++j) {
                uint32_t w = mask[wwb + j * 2 + (lane >> 5)];
                livem |= ((w >> (lane & 31)) & 1u) << j;
            }
            float px[PT], py[PT], pz[PT]; int ov[PT];
            ld8(pbase, px, py, pz, ov);
            uint32_t keepm = 0;
            float dmin = INFINITY; int imin = 0;
            #pragma unroll
            for (int j = 0; j < PT; ++j) {
                if ((livem >> j) & 1u) {
                    float dt = ax*px[j] + ay*py[j] + az*pz[j] - b;
                    if (dt < EPS_SEP) {                 // !(dt >= EPS_SEP)
                        keepm |= (1u << j);
                        float p2 = px[j]*px[j] + py[j]*py[j] + pz[j]*pz[j];
                        float tp = tx*px[j] + ty*py[j] + tz*pz[j];
                        float d2 = t2 + p2 - 2.0f*tp;
                        if (d2 < dmin || (d2 == dmin && ov[j] < imin)) {
                            dmin = d2; imin = ov[j];
                        }
                    }
                }
            }
            #pragma unroll
            for (int j = 0; j < PT; ++j) {
                unsigned long long bal = __ballot(((keepm >> j) & 1u) != 0u);
                if (lane == 0)       mask[wwb + j*2]     = (uint32_t)bal;
                else if (lane == 32) mask[wwb + j*2 + 1] = (uint32_t)(bal >> 32);
            }
            writeChunk(c, keepm, dmin, imin, px, py, pz);
        }
    };

    initScan();
    int2 rc = finish();
    int idx = rc.x, count = rc.y;

    for (int k = 0; k < MAX_ITERS; ++k) {
        // Solo endgame: compact survivors to LDS coords, wave 0 finishes.
        if (count <= SOLO_CAP && count > 0) {
            if (tid == 0) cnt[0] = 0;
            __syncthreads();
            for (int s = 0; s < stepsA; ++s) {          // sweep own chunks
                const int c = s * NW + wv;
                if (ccn[c] == 0) continue;
                const int pbase = s * (PT * BLOCK) + wv * (PT * 64) + lane;
                const int wwb   = s * (PT * BLOCK / 32) + wv * (PT * 2);
                uint32_t livem = 0;
                #pragma unroll
                for (int j = 0; j < PT; ++j) {
                    uint32_t w = mask[wwb + j * 2 + (lane >> 5)];
                    livem |= ((w >> (lane & 31)) & 1u) << j;
                }
                float px[PT], py[PT], pz[PT]; int ov[PT];
                ld8(pbase, px, py, pz, ov);
                int cl = (int)__popc(livem);
                int incl = cl;
                #pragma unroll
                for (int off = 1; off < 64; off <<= 1) {
                    int o = __shfl_up(incl, off, 64);
                    if (lane >= off) incl += o;
                }
                const int excl = incl - cl;
                const int tot  = __shfl(incl, 63, 64);
                int wb = 0;
                if (lane == 0) wb = atomicAdd(cnt, tot);
                wb = __shfl(wb, 0, 64);
                int pos = wb + excl;
                #pragma unroll
                for (int j = 0; j < PT; ++j) {
                    if ((livem >> j) & 1u) {
                        slist[pos] = ov[j];
                        lx[pos] = px[j]; ly[pos] = py[j]; lz[pos] = pz[j];
                        ++pos;
                    }
                }
            }
            __syncthreads();
            if (wv != 0) return;                        // LDS persists
            for (; k < MAX_ITERS; ++k) {
                const float* cp = pc + 3 * (size_t)idx;
                const float cx = cp[0], cy = cp[1], cz = cp[2];
                const float vx = cx - tx, vy = cy - ty, vz = cz - tz;
                const float nrm = sqrtf(vx*vx + vy*vy + vz*vz);
                const float den = nrm + EPS_NORM;
                const float ax = vx / den, ay = vy / den, az = vz / den;
                const float b  = ax*cx + ay*cy + az*cz;
                if (count == 0) {
                    for (int q = lane; q < MAX_ITERS - k; q += 64) {
                        const int kk = k + q;
                        const size_t oa = ((size_t)kk * M + m) * 3;
                        out_a[oa+0] = ax; out_a[oa+1] = ay; out_a[oa+2] = az;
                        out_b[(size_t)kk * M + m] = b;
                    }
                    return;
                }
                if (lane == 0) {
                    const size_t oa = ((size_t)k * M + m) * 3;
                    out_a[oa+0] = ax; out_a[oa+1] = ay; out_a[oa+2] = az;
                    out_b[(size_t)k * M + m] = b;
                }
                if (k + 1 < MAX_ITERS) {
                    float dmin = INFINITY; int imin = 0; int wcur = 0;
                    for (int e0 = 0; e0 < count; e0 += 64) {
                        const int e = e0 + lane;
                        bool keep = false; int j = 0;
                        float d2v = 0.f, px = 0.f, py = 0.f, pz = 0.f;
                        if (e < count) {
                            j = slist[e];
                            px = lx[e]; py = ly[e]; pz = lz[e];
                            float dt = ax*px + ay*py + az*pz - b;
                            if (dt < EPS_SEP) {
                                keep = true;
                                float p2 = px*px + py*py + pz*pz;
                                float tp = tx*px + ty*py + tz*pz;
                                d2v = t2 + p2 - 2.0f*tp;
                            }
                        }
                        // in-place compact: pos < wcur+64 <= e0+64; chunk
                        // [e0,e0+64) already in registers.
                        unsigned long long bal = __ballot(keep);
                        int pos = wcur + (int)__popcll(bal & ((1ull << lane) - 1ull));
                        if (keep) {
                            slist[pos] = j;
                            lx[pos] = px; ly[pos] = py; lz[pos] = pz;
                            if (d2v < dmin || (d2v == dmin && j < imin)) {
                                dmin = d2v; imin = j;
                            }
                        }
                        wcur += (int)__popcll(bal);
                    }
                    #pragma unroll
                    for (int off = 32; off > 0; off >>= 1) {
                        float od = __shfl_down(dmin, off, 64);
                        int   oi = __shfl_down(imin, off, 64);
                        if (od < dmin || (od == dmin && oi < imin)) { dmin = od; imin = oi; }
                    }
                    idx = __shfl(imin, 0, 64);
                    count = wcur;
                }
            }
            return;
        }

        const float* cp = pc + 3 * (size_t)idx;         // idx = ORIGINAL index
        const float cx = cp[0], cy = cp[1], cz = cp[2];
        const float vx = cx - tx, vy = cy - ty, vz = cz - tz;
        const float nrm = sqrtf(vx*vx + vy*vy + vz*vz);
        const float den = nrm + EPS_NORM;
        const float ax = vx / den, ay = vy / den, az = vz / den;
        const float b  = ax*cx + ay*cy + az*cz;         // b = sum(a * closest)

        if (count == 0) {                               // constant tail
            for (int q = tid; q < MAX_ITERS - k; q += BLOCK) {
                const int kk = k + q;
                const size_t oa = ((size_t)kk * M + m) * 3;
                out_a[oa+0] = ax; out_a[oa+1] = ay; out_a[oa+2] = az;
                out_b[(size_t)kk * M + m] = b;
            }
            return;
        }
        if (tid == 0) {
            const size_t oa = ((size_t)k * M + m) * 3;
            out_a[oa+0] = ax; out_a[oa+1] = ay; out_a[oa+2] = az;
            out_b[(size_t)k * M + m] = b;
        }
        if (k + 1 < MAX_ITERS) {                        // last update unobservable
            stepScan(ax, ay, az, b);
            rc = finish();
            idx = rc.x; count = rc.y;
        }
    }
}

extern "C" void kernel_launch(void* const* d_in, const int* in_sizes, int n_in,
                              void* d_out, int out_size, void* d_ws, size_t ws_size,
                              hipStream_t stream) {
    const float* pc = (const float*)d_in[0];
    const float* tg = (const float*)d_in[1];
    float* out = (float*)d_out;
    const int N = in_sizes[0] / 3;
    const int M = in_sizes[1] / 3;
    const int stepsA = (N + BLOCK * PT - 1) / (BLOCK * PT);
    const int NC     = stepsA * NW;
    const int maskW  = stepsA * (PT * BLOCK / 32);
    const size_t smemW = (size_t)maskW + 9u * NC + 3u * NW + 3u
                       + 4u * SOLO_CAP;                 // words
    const size_t smem  = smemW * sizeof(uint32_t);      // ~72 KB at N=200k
    const size_t pkB   = (size_t)N * sizeof(float4);
    const size_t binB  = 2 * (size_t)NBINS * sizeof(int);

    int wsmode = 0;                                     // 0 raw, 1 identity, 2 sorted
    if (d_ws && ws_size >= pkB + binB) wsmode = 2;
    else if (d_ws && ws_size >= pkB)   wsmode = 1;
    float4* pk     = (float4*)d_ws;
    int*    binCnt = (int*)((char*)d_ws + pkB);
    int*    binCur = binCnt + NBINS;

    hipFuncSetAttribute((const void*)convex_plane_kernel<true>,
                        hipFuncAttributeMaxDynamicSharedMemorySize, (int)smem);
    hipFuncSetAttribute((const void*)convex_plane_kernel<false>,
                        hipFuncAttributeMaxDynamicSharedMemorySize, (int)smem);

    if (wsmode == 2) {
        const int tpb = 256;
        const int vthreads = (N + 3) / 4;
        hipMemsetAsync(binCnt, 0, NBINS * sizeof(int), stream);
        hist_bins<<<(vthreads + tpb - 1) / tpb, tpb, 0, stream>>>(pc, binCnt, N);
        scan_bins<<<1, 1024, 0, stream>>>(binCnt, binCur);
        scatter_bins<<<(vthreads + tpb - 1) / tpb, tpb, 0, stream>>>(pc, pk,
                                                                     binCur, N);
        convex_plane_kernel<true><<<M, BLOCK, smem, stream>>>(
            pc, pk, tg, out, N, M, stepsA);
    } else if (wsmode == 1) {
        pack_identity<<<(N + 255) / 256, 256, 0, stream>>>(pc, pk, N);
        convex_plane_kernel<true><<<M, BLOCK, smem, stream>>>(
            pc, pk, tg, out, N, M, stepsA);
    } else {
        convex_plane_kernel<false><<<M, BLOCK, smem, stream>>>(
            pc, nullptr, tg, out, N, M, stepsA);
    }
}